// Round 1
// baseline (194.240 us; speedup 1.0000x reference)
//
#include <hip/hip_runtime.h>
#include <math.h>

#define NUM_POS 17
#define H1 128
#define H2 64
#define SEQ 8192
#define BATCH 64

// Transpose W2 (128x64 row-major) -> W2t (64x128) in workspace, so the
// main kernel's layer-2 inner loop reads contiguous weights (merges to
// s_load_dwordx16 instead of 128 strided scalar loads per k).
__global__ void transpose_w2_kernel(const float* __restrict__ W2,
                                    float* __restrict__ W2t) {
    int idx = blockIdx.x * blockDim.x + threadIdx.x;  // 0..8191
    if (idx < H1 * H2) {
        int k = idx >> 7;    // 0..63
        int h = idx & 127;   // 0..127
        W2t[idx] = W2[h * H2 + k];
    }
}

template <bool USE_WT>
__global__ __launch_bounds__(256, 2)
void lpe_kernel(const float* __restrict__ pos,
                const float* __restrict__ W1, const float* __restrict__ b1,
                const float* __restrict__ W2, const float* __restrict__ b2,
                const float* __restrict__ W3, const float* __restrict__ b3,
                const float* __restrict__ W2t,
                float* __restrict__ out) {
    // Each block: one batch b, one chunk of 256 consecutive s positions.
    const int chunk = blockIdx.x & 31;   // 32 chunks cover s in [0, 8190)
    const int b     = blockIdx.x >> 5;   // 0..63
    const int s0    = chunk * 256;
    const int tid   = threadIdx.x;

    __shared__ float spos[258 * NUM_POS];  // 17.2 KB; rows s0 .. s0+257

    const int nrows  = min(258, SEQ - s0);
    const int nelems = nrows * NUM_POS;
    const float* src = pos + ((size_t)b * SEQ + s0) * NUM_POS;
    for (int i = tid; i < nelems; i += 256) spos[i] = src[i];
    __syncthreads();

    const int s = s0 + tid;
    if (s > SEQ - 3) return;  // valid rows: s in [0, 8189]

    // ---- layer 1: h1 = relu(window(51) @ W1 + b1), h1 kept in VGPRs ----
    float h1[H1];
    #pragma unroll
    for (int h = 0; h < H1; ++h) h1[h] = b1[h];

    for (int j = 0; j < 3; ++j) {
        const float* wbase = W1 + (j * NUM_POS) * H1;   // uniform -> s_load
        const float* prow  = spos + (tid + j) * NUM_POS; // stride 17: bank-safe
        for (int i = 0; i < NUM_POS; ++i) {
            const float x = prow[i];
            const float* w = wbase + i * H1;
            #pragma unroll
            for (int h = 0; h < H1; ++h) h1[h] = fmaf(x, w[h], h1[h]);
        }
    }
    #pragma unroll
    for (int h = 0; h < H1; ++h) h1[h] = fmaxf(h1[h], 0.0f);

    // ---- layers 2+3 fused: acc = sum_k relu(h1 . W2[:,k] + b2[k]) * W3[k] ----
    float acc = b3[0];
    for (int k = 0; k < H2; ++k) {
        // 4 partial sums break the 128-deep dependent FMA chain
        float t0 = b2[k], t1 = 0.0f, t2 = 0.0f, t3 = 0.0f;
        if (USE_WT) {
            const float* w = W2t + k * H1;  // contiguous, uniform -> s_load x16
            #pragma unroll
            for (int h = 0; h < H1; h += 4) {
                t0 = fmaf(h1[h + 0], w[h + 0], t0);
                t1 = fmaf(h1[h + 1], w[h + 1], t1);
                t2 = fmaf(h1[h + 2], w[h + 2], t2);
                t3 = fmaf(h1[h + 3], w[h + 3], t3);
            }
        } else {
            #pragma unroll
            for (int h = 0; h < H1; h += 4) {
                t0 = fmaf(h1[h + 0], W2[(h + 0) * H2 + k], t0);
                t1 = fmaf(h1[h + 1], W2[(h + 1) * H2 + k], t1);
                t2 = fmaf(h1[h + 2], W2[(h + 2) * H2 + k], t2);
                t3 = fmaf(h1[h + 3], W2[(h + 3) * H2 + k], t3);
            }
        }
        float t = fmaxf((t0 + t1) + (t2 + t3), 0.0f);
        acc = fmaf(t, W3[k], acc);
    }

    out[(size_t)b * (SEQ - 2) + s] = 1.0f / (1.0f + expf(-acc));
}

extern "C" void kernel_launch(void* const* d_in, const int* in_sizes, int n_in,
                              void* d_out, int out_size, void* d_ws, size_t ws_size,
                              hipStream_t stream) {
    const float* pos = (const float*)d_in[0];
    const float* W1  = (const float*)d_in[1];
    const float* b1  = (const float*)d_in[2];
    const float* W2  = (const float*)d_in[3];
    const float* b2  = (const float*)d_in[4];
    const float* W3  = (const float*)d_in[5];
    const float* b3  = (const float*)d_in[6];
    float* out = (float*)d_out;

    const bool use_wt = ws_size >= (size_t)(H1 * H2 * sizeof(float));
    float* W2t = (float*)d_ws;

    const int grid = BATCH * 32;  // 64 batches x 32 chunks of 256 rows

    if (use_wt) {
        transpose_w2_kernel<<<(H1 * H2 + 255) / 256, 256, 0, stream>>>(W2, W2t);
        lpe_kernel<true><<<grid, 256, 0, stream>>>(pos, W1, b1, W2, b2, W3, b3,
                                                   W2t, out);
    } else {
        lpe_kernel<false><<<grid, 256, 0, stream>>>(pos, W1, b1, W2, b2, W3, b3,
                                                    W2, out);
    }
}

// Round 2
// 69.442 us; speedup vs baseline: 2.7971x; 2.7971x over previous
//
#include <hip/hip_runtime.h>
#include <hip/hip_bf16.h>
#include <math.h>

#define NUM_POS 17
#define SEQ 8192
#define BATCH 64
#define H1 128
#define H2 64

typedef __attribute__((ext_vector_type(8)))  short        s16x8;
typedef __attribute__((ext_vector_type(16))) float        f32x16;
typedef __attribute__((ext_vector_type(4)))  unsigned int u32x4;

static __device__ __forceinline__ unsigned pkbf(float a, float b) {
    unsigned short ua = __builtin_bit_cast(unsigned short, __float2bfloat16(a));
    unsigned short ub = __builtin_bit_cast(unsigned short, __float2bfloat16(b));
    return (unsigned)ua | ((unsigned)ub << 16);
}

static __device__ __forceinline__ f32x16 zero16() {
    f32x16 z;
    #pragma unroll
    for (int i = 0; i < 16; ++i) z[i] = 0.0f;
    return z;
}

// ---- prep: W1tb[h][64] = W1^T padded (col51 = b1), W2tb[h2][144] = W2^T padded (col128 = b2)
__global__ void prep_kernel(const float* __restrict__ W1, const float* __restrict__ b1,
                            const float* __restrict__ W2, const float* __restrict__ b2,
                            __hip_bfloat16* __restrict__ W1tb,
                            __hip_bfloat16* __restrict__ W2tb) {
    int i = blockIdx.x * 256 + threadIdx.x;
    if (i < H1 * 64) {
        int h = i >> 6, k = i & 63;
        float v = (k < 51) ? W1[k * H1 + h] : ((k == 51) ? b1[h] : 0.0f);
        W1tb[i] = __float2bfloat16(v);
    } else if (i < H1 * 64 + H2 * 144) {
        int j = i - H1 * 64;
        int h2 = j / 144, k = j - h2 * 144;
        float v = (k < 128) ? W2[k * H2 + h2] : ((k == 128) ? b2[h2] : 0.0f);
        W2tb[j] = __float2bfloat16(v);
    }
}

// ---- main: one block = 4 waves x 32 output rows = 128 rows of one batch.
__global__ __launch_bounds__(256, 2)
void lpe_mfma_kernel(const float* __restrict__ pos,
                     const __hip_bfloat16* __restrict__ W1tb,
                     const __hip_bfloat16* __restrict__ W2tb,
                     const float* __restrict__ W3,
                     const float* __restrict__ b3,
                     float* __restrict__ out) {
    __shared__ float sp[4 * 592];  // per-wave 592 floats (578 used + OOB pad)

    const int tid  = threadIdx.x;
    const int wid  = tid >> 6;
    const int lane = tid & 63;
    const int ml   = lane & 31;   // output row within wave tile (MFMA col)
    const int hi   = lane >> 5;   // half-wave index

    const int batch = blockIdx.x >> 6;
    const int blk   = blockIdx.x & 63;
    const int srow0 = blk * 128 + wid * 32;

    float* spw = sp + wid * 592;

    // per-lane W3 values matching C2' layout: h2 = 32f + (r&3) + 8(r>>2) + 4hi
    float w3v[2][16];
    {
        const float* w3b = W3 + 4 * hi;
        #pragma unroll
        for (int f = 0; f < 2; ++f)
            #pragma unroll
            for (int r = 0; r < 16; ++r)
                w3v[f][r] = w3b[f * 32 + (r & 3) + 8 * (r >> 2)];
    }
    const float b3v = b3[0];

    // constant bias B-fragment for GEMM2 k-step 8 (k=128 -> 1.0, rest 0)
    u32x4 b2cu; b2cu[0] = (hi == 0) ? 0x3f80u : 0u; b2cu[1] = 0u; b2cu[2] = 0u; b2cu[3] = 0u;
    const s16x8 B2C = __builtin_bit_cast(s16x8, b2cu);

    // ---- stage 34 rows x 17 floats (flat 578) into wave-private LDS ----
    {
        const float* src = pos + ((size_t)batch * SEQ + srow0) * NUM_POS;
        const int lim = (SEQ - srow0) * NUM_POS;  // available elements
        #pragma unroll
        for (int it = 0; it < 10; ++it) {
            int i = it * 64 + lane;
            if (i < 578) spw[i] = (i < lim) ? src[i] : 0.0f;
        }
    }
    // wave-private LDS: same-wave program order suffices, no barrier.

    // ---- B1 fragments: window(m) = contiguous pos_flat[m*17 ..], 8 floats each ----
    const float* wbase = spw + ml * NUM_POS + 8 * hi;
    u32x4 B1u[4];
    #pragma unroll
    for (int kk = 0; kk < 4; ++kk) {
        float x[8];
        #pragma unroll
        for (int j = 0; j < 8; ++j) {
            if (kk < 3) {
                x[j] = wbase[kk * 16 + j];          // k <= 47 always valid
            } else {
                if (j < 3) {                        // hi=0: k=48..50 real; hi=1: k=56..58 -> 0
                    float v = wbase[48 + j];
                    x[j] = hi ? 0.0f : v;
                } else if (j == 3) {                // hi=0: k=51 -> bias 1.0; hi=1 -> 0
                    x[j] = hi ? 0.0f : 1.0f;
                } else {
                    x[j] = 0.0f;                    // k >= 52 padding
                }
            }
        }
        u32x4 u;
        u[0] = pkbf(x[0], x[1]); u[1] = pkbf(x[2], x[3]);
        u[2] = pkbf(x[4], x[5]); u[3] = pkbf(x[6], x[7]);
        B1u[kk] = u;
    }

    // ---- GEMM1': C1'[h][m] = sum_k W1^T[h][k] * win[m][k]  (4 hf frags, K=64) ----
    f32x16 acc1[4];
    #pragma unroll
    for (int hf = 0; hf < 4; ++hf) acc1[hf] = zero16();

    #pragma unroll
    for (int hf = 0; hf < 4; ++hf) {
        #pragma unroll
        for (int kk = 0; kk < 4; ++kk) {
            s16x8 a = *reinterpret_cast<const s16x8*>(
                W1tb + ((hf * 32 + ml) * 64 + kk * 16 + hi * 8));
            acc1[hf] = __builtin_amdgcn_mfma_f32_32x32x16_bf16(
                a, __builtin_bit_cast(s16x8, B1u[kk]), acc1[hf], 0, 0, 0);
        }
    }

    // relu (h1)
    #pragma unroll
    for (int hf = 0; hf < 4; ++hf)
        #pragma unroll
        for (int r = 0; r < 16; ++r)
            acc1[hf][r] = fmaxf(acc1[hf][r], 0.0f);

    // ---- GEMM2': per k-step, repack C1' -> B2 frag (cvt_pk + shfl_xor 32), then MFMA ----
    f32x16 acc2[2];
    acc2[0] = zero16(); acc2[1] = zero16();

    #pragma unroll
    for (int kk = 0; kk < 8; ++kk) {
        // pack pairs from even-block e=2kk and odd-block e=2kk+1 (static indices)
        unsigned pA0, pA1, pB0, pB1;
        {
            const int e = 2 * kk, hf = e >> 2, r = (e & 3) * 4;
            pA0 = pkbf(acc1[hf][r],     acc1[hf][r + 1]);
            pA1 = pkbf(acc1[hf][r + 2], acc1[hf][r + 3]);
        }
        {
            const int e = 2 * kk + 1, hf = e >> 2, r = (e & 3) * 4;
            pB0 = pkbf(acc1[hf][r],     acc1[hf][r + 1]);
            pB1 = pkbf(acc1[hf][r + 2], acc1[hf][r + 3]);
        }
        // exchange the half destined for the partner half-wave
        unsigned s0 = hi ? pA0 : pB0;
        unsigned s1 = hi ? pA1 : pB1;
        unsigned r0 = (unsigned)__shfl_xor((int)s0, 32);
        unsigned r1 = (unsigned)__shfl_xor((int)s1, 32);
        u32x4 bu;
        bu[0] = hi ? r0 : pA0;
        bu[1] = hi ? r1 : pA1;
        bu[2] = hi ? pB0 : r0;
        bu[3] = hi ? pB1 : r1;
        const s16x8 bfrag = __builtin_bit_cast(s16x8, bu);

        #pragma unroll
        for (int f = 0; f < 2; ++f) {
            s16x8 a = *reinterpret_cast<const s16x8*>(
                W2tb + ((f * 32 + ml) * 144 + kk * 16 + hi * 8));
            acc2[f] = __builtin_amdgcn_mfma_f32_32x32x16_bf16(a, bfrag, acc2[f], 0, 0, 0);
        }
    }
    // bias k-step (k=128 column holds b2)
    #pragma unroll
    for (int f = 0; f < 2; ++f) {
        s16x8 a = *reinterpret_cast<const s16x8*>(
            W2tb + ((f * 32 + ml) * 144 + 128 + hi * 8));
        acc2[f] = __builtin_amdgcn_mfma_f32_32x32x16_bf16(a, B2C, acc2[f], 0, 0, 0);
    }

    // ---- layer 3 + sigmoid epilogue (VALU): out[m] = sig(sum_h2 relu(h2)*W3 + b3) ----
    float part = 0.0f;
    #pragma unroll
    for (int f = 0; f < 2; ++f)
        #pragma unroll
        for (int r = 0; r < 16; ++r)
            part = fmaf(fmaxf(acc2[f][r], 0.0f), w3v[f][r], part);
    part += __shfl_xor(part, 32);  // sum the two half-wave h2 partitions

    if (hi == 0) {
        const int grow = srow0 + ml;
        if (grow < SEQ - 2) {
            float v = part + b3v;
            out[(size_t)batch * (SEQ - 2) + grow] = 1.0f / (1.0f + __expf(-v));
        }
    }
}

extern "C" void kernel_launch(void* const* d_in, const int* in_sizes, int n_in,
                              void* d_out, int out_size, void* d_ws, size_t ws_size,
                              hipStream_t stream) {
    const float* pos = (const float*)d_in[0];
    const float* W1  = (const float*)d_in[1];
    const float* b1  = (const float*)d_in[2];
    const float* W2  = (const float*)d_in[3];
    const float* b2  = (const float*)d_in[4];
    const float* W3  = (const float*)d_in[5];
    const float* b3  = (const float*)d_in[6];
    float* out = (float*)d_out;

    __hip_bfloat16* W1tb = (__hip_bfloat16*)d_ws;                       // 128*64 bf16 = 16 KB
    __hip_bfloat16* W2tb = (__hip_bfloat16*)((char*)d_ws + 16384);      // 64*144 bf16 = 18 KB

    const int prep_elems = H1 * 64 + H2 * 144;  // 17408
    prep_kernel<<<(prep_elems + 255) / 256, 256, 0, stream>>>(W1, b1, W2, b2, W1tb, W2tb);

    // 64 batches x 64 blocks of 128 rows
    lpe_mfma_kernel<<<BATCH * 64, 256, 0, stream>>>(pos, W1tb, W2tb, W3, b3, out);
}

// Round 3
// 50.435 us; speedup vs baseline: 3.8512x; 1.3768x over previous
//
#include <hip/hip_runtime.h>
#include <hip/hip_bf16.h>
#include <math.h>

#define NUM_POS 17
#define SEQ 8192
#define BATCH 64
#define H1 128
#define H2 64
#define TILE_F 592  // floats per 32-row tile region (578 used + pad)

typedef __attribute__((ext_vector_type(8)))  short        s16x8;
typedef __attribute__((ext_vector_type(16))) float        f32x16;
typedef __attribute__((ext_vector_type(4)))  unsigned int u32x4;
typedef __attribute__((ext_vector_type(4)))  float        f32x4;

static __device__ __forceinline__ unsigned pkbf(float a, float b) {
    unsigned short ua = __builtin_bit_cast(unsigned short, __float2bfloat16(a));
    unsigned short ub = __builtin_bit_cast(unsigned short, __float2bfloat16(b));
    return (unsigned)ua | ((unsigned)ub << 16);
}

static __device__ __forceinline__ f32x16 zero16() {
    f32x16 z;
    #pragma unroll
    for (int i = 0; i < 16; ++i) z[i] = 0.0f;
    return z;
}

// prep: W1tb[h][64] = W1^T padded (col51 = b1).
// W2tb[h2][144]: cols 0..127 hold W2^T with the k-dimension PERMUTED so that
// GEMM2's B-fragment is a contiguous slice of the GEMM1 accumulator:
//   perm(k): kk=k>>4, hb=(k>>3)&1, j=k&7
//   perm(k) = (kk&3)*32 + 8*(((kk>>2)<<1)|(j>>2)) + (j&3) + 4*hb
// col 128 = b2, cols 129..143 = 0.
__global__ void prep_kernel(const float* __restrict__ W1, const float* __restrict__ b1,
                            const float* __restrict__ W2, const float* __restrict__ b2,
                            __hip_bfloat16* __restrict__ W1tb,
                            __hip_bfloat16* __restrict__ W2tb) {
    int i = blockIdx.x * 256 + threadIdx.x;
    if (i < H1 * 64) {
        int h = i >> 6, k = i & 63;
        float v = (k < 51) ? W1[k * H1 + h] : ((k == 51) ? b1[h] : 0.0f);
        W1tb[i] = __float2bfloat16(v);
    } else if (i < H1 * 64 + H2 * 144) {
        int j = i - H1 * 64;
        int h2 = j / 144, k = j - h2 * 144;
        float v;
        if (k < 128) {
            int kk = k >> 4, hb = (k >> 3) & 1, jj = k & 7;
            int hperm = (kk & 3) * 32 + 8 * (((kk >> 2) << 1) | (jj >> 2)) + (jj & 3) + 4 * hb;
            v = W2[hperm * H2 + h2];
        } else {
            v = (k == 128) ? b2[h2] : 0.0f;
        }
        W2tb[j] = __float2bfloat16(v);
    }
}

// main: 1024 blocks x 4 waves; each wave computes 4 tiles of 32 output rows.
__global__ __launch_bounds__(256, 2)
void lpe_mfma_kernel(const float* __restrict__ pos,
                     const __hip_bfloat16* __restrict__ W1tb,
                     const __hip_bfloat16* __restrict__ W2tb,
                     const float* __restrict__ W3,
                     const float* __restrict__ b3,
                     float* __restrict__ out) {
    __shared__ float sp[16 * TILE_F];  // 4 waves x 4 tiles = 37.9 KB

    const int tid  = threadIdx.x;
    const int wid  = tid >> 6;
    const int lane = tid & 63;
    const int ml   = lane & 31;
    const int hi   = lane >> 5;

    const int batch = blockIdx.x >> 4;  // 64 batches x 16 blocks
    const int blk   = blockIdx.x & 15;
    const int wrow0 = blk * 512 + wid * 128;

    // ---- stage all 4 tiles (float4, 16B-aligned bases), wave-private LDS ----
    #pragma unroll
    for (int t = 0; t < 4; ++t) {
        float* dst = sp + (wid * 4 + t) * TILE_F;
        const int srow0 = wrow0 + t * 32;
        const float* src = pos + ((size_t)batch * SEQ + srow0) * NUM_POS;
        const int lim = (SEQ - srow0) * NUM_POS;  // >= 544; 544 only at global tail
        #pragma unroll
        for (int it = 0; it < 3; ++it) {
            int i = it * 64 + lane;
            if (i < 144) {
                f32x4 v;
                if (i * 4 + 4 <= lim) {
                    v = *reinterpret_cast<const f32x4*>(src + i * 4);
                } else {
                    v[0] = v[1] = v[2] = v[3] = 0.0f;
                }
                *reinterpret_cast<f32x4*>(dst + i * 4) = v;
            }
        }
        if (lane < 2) {
            int i = 576 + lane;
            dst[i] = (i < lim) ? src[i] : 0.0f;
        }
    }
    // same-wave ds_write -> ds_read: compiler-inserted lgkmcnt ordering suffices.

    // per-lane W3 values matching C2' layout: h2 = 32f + (r&3) + 8(r>>2) + 4hi
    float w3v[2][16];
    {
        const float* w3b = W3 + 4 * hi;
        #pragma unroll
        for (int f = 0; f < 2; ++f)
            #pragma unroll
            for (int r = 0; r < 16; ++r)
                w3v[f][r] = w3b[f * 32 + (r & 3) + 8 * (r >> 2)];
    }
    const float b3v = b3[0];

    // constant bias B-fragment for GEMM2's k=128 step
    u32x4 b2cu; b2cu[0] = (hi == 0) ? 0x3f80u : 0u; b2cu[1] = 0u; b2cu[2] = 0u; b2cu[3] = 0u;
    const s16x8 B2C = __builtin_bit_cast(s16x8, b2cu);

    #pragma unroll 1
    for (int t = 0; t < 4; ++t) {
        const float* spw = sp + (wid * 4 + t) * TILE_F;
        const int srow0 = wrow0 + t * 32;

        // ---- B1 fragments: window(m) = contiguous 51 floats at m*17 ----
        const float* wbase = spw + ml * NUM_POS + 8 * hi;
        u32x4 B1u[4];
        #pragma unroll
        for (int kk = 0; kk < 4; ++kk) {
            float x[8];
            #pragma unroll
            for (int j = 0; j < 8; ++j) {
                if (kk < 3) {
                    x[j] = wbase[kk * 16 + j];
                } else {
                    if (j < 3) {
                        float v = wbase[48 + j];
                        x[j] = hi ? 0.0f : v;       // hi=1 slots are k=56..63 pad
                    } else if (j == 3) {
                        x[j] = hi ? 0.0f : 1.0f;    // k=51 bias column
                    } else {
                        x[j] = 0.0f;
                    }
                }
            }
            u32x4 u;
            u[0] = pkbf(x[0], x[1]); u[1] = pkbf(x[2], x[3]);
            u[2] = pkbf(x[4], x[5]); u[3] = pkbf(x[6], x[7]);
            B1u[kk] = u;
        }

        // ---- GEMM1': C1'[h][m], K=64 ----
        f32x16 acc1[4];
        #pragma unroll
        for (int hf = 0; hf < 4; ++hf) acc1[hf] = zero16();
        #pragma unroll
        for (int hf = 0; hf < 4; ++hf) {
            #pragma unroll
            for (int kk = 0; kk < 4; ++kk) {
                s16x8 a = *reinterpret_cast<const s16x8*>(
                    W1tb + ((hf * 32 + ml) * 64 + kk * 16 + hi * 8));
                acc1[hf] = __builtin_amdgcn_mfma_f32_32x32x16_bf16(
                    a, __builtin_bit_cast(s16x8, B1u[kk]), acc1[hf], 0, 0, 0);
            }
        }

        // ---- GEMM2': thanks to the W2 k-permutation, B-frag for step kk is just
        // relu(acc1[kk&3][8*(kk>>2) .. +7]) packed contiguously. No shuffles. ----
        f32x16 acc2[2];
        acc2[0] = zero16(); acc2[1] = zero16();
        #pragma unroll
        for (int kk = 0; kk < 8; ++kk) {
            const int hf = kk & 3;
            const int rb = (kk >> 2) * 8;
            u32x4 bu;
            bu[0] = pkbf(fmaxf(acc1[hf][rb + 0], 0.0f), fmaxf(acc1[hf][rb + 1], 0.0f));
            bu[1] = pkbf(fmaxf(acc1[hf][rb + 2], 0.0f), fmaxf(acc1[hf][rb + 3], 0.0f));
            bu[2] = pkbf(fmaxf(acc1[hf][rb + 4], 0.0f), fmaxf(acc1[hf][rb + 5], 0.0f));
            bu[3] = pkbf(fmaxf(acc1[hf][rb + 6], 0.0f), fmaxf(acc1[hf][rb + 7], 0.0f));
            const s16x8 bfrag = __builtin_bit_cast(s16x8, bu);
            #pragma unroll
            for (int f = 0; f < 2; ++f) {
                s16x8 a = *reinterpret_cast<const s16x8*>(
                    W2tb + ((f * 32 + ml) * 144 + kk * 16 + hi * 8));
                acc2[f] = __builtin_amdgcn_mfma_f32_32x32x16_bf16(a, bfrag, acc2[f], 0, 0, 0);
            }
        }
        #pragma unroll
        for (int f = 0; f < 2; ++f) {
            s16x8 a = *reinterpret_cast<const s16x8*>(
                W2tb + ((f * 32 + ml) * 144 + 128 + hi * 8));
            acc2[f] = __builtin_amdgcn_mfma_f32_32x32x16_bf16(a, B2C, acc2[f], 0, 0, 0);
        }

        // ---- layer 3 + sigmoid epilogue ----
        float part = 0.0f;
        #pragma unroll
        for (int f = 0; f < 2; ++f)
            #pragma unroll
            for (int r = 0; r < 16; ++r)
                part = fmaf(fmaxf(acc2[f][r], 0.0f), w3v[f][r], part);
        part += __shfl_xor(part, 32);  // combine the two half-wave h2 partitions

        if (hi == 0) {
            const int grow = srow0 + ml;
            if (grow < SEQ - 2) {
                float v = part + b3v;
                out[(size_t)batch * (SEQ - 2) + grow] = 1.0f / (1.0f + __expf(-v));
            }
        }
    }
}

extern "C" void kernel_launch(void* const* d_in, const int* in_sizes, int n_in,
                              void* d_out, int out_size, void* d_ws, size_t ws_size,
                              hipStream_t stream) {
    const float* pos = (const float*)d_in[0];
    const float* W1  = (const float*)d_in[1];
    const float* b1  = (const float*)d_in[2];
    const float* W2  = (const float*)d_in[3];
    const float* b2  = (const float*)d_in[4];
    const float* W3  = (const float*)d_in[5];
    const float* b3  = (const float*)d_in[6];
    float* out = (float*)d_out;

    __hip_bfloat16* W1tb = (__hip_bfloat16*)d_ws;                   // 8192 bf16 = 16 KB
    __hip_bfloat16* W2tb = (__hip_bfloat16*)((char*)d_ws + 16384);  // 9216 bf16 = 18 KB

    const int prep_elems = H1 * 64 + H2 * 144;  // 17408
    prep_kernel<<<(prep_elems + 255) / 256, 256, 0, stream>>>(W1, b1, W2, b2, W1tb, W2tb);

    // 64 batches x 16 blocks; each block = 4 waves x 4 tiles x 32 rows = 512 rows
    lpe_mfma_kernel<<<BATCH * 16, 256, 0, stream>>>(pos, W1tb, W2tb, W3, b3, out);
}

// Round 4
// 47.296 us; speedup vs baseline: 4.1069x; 1.0664x over previous
//
#include <hip/hip_runtime.h>
#include <hip/hip_bf16.h>
#include <math.h>

#define NUM_POS 17
#define SEQ 8192
#define BATCH 64
#define H1 128
#define H2 64
#define TILE_F 592  // floats per 32-row tile region (578 used + pad)

typedef __attribute__((ext_vector_type(8)))  short        s16x8;
typedef __attribute__((ext_vector_type(16))) float        f32x16;
typedef __attribute__((ext_vector_type(4)))  unsigned int u32x4;
typedef __attribute__((ext_vector_type(4)))  float        f32x4;

static __device__ __forceinline__ unsigned pkbf(float a, float b) {
    unsigned short ua = __builtin_bit_cast(unsigned short, __float2bfloat16(a));
    unsigned short ub = __builtin_bit_cast(unsigned short, __float2bfloat16(b));
    return (unsigned)ua | ((unsigned)ub << 16);
}

static __device__ __forceinline__ f32x16 zero16() {
    f32x16 z;
    #pragma unroll
    for (int i = 0; i < 16; ++i) z[i] = 0.0f;
    return z;
}

// prep:
//  W1tb[h][64]  = W1^T padded (col 51 = b1, cols 52..63 = 0)
//  W2tb[h2][144] = W2^T with k-dim permuted to match the C1' fragment order
//                  (col 128 = b2, cols 129..143 = 0)
//  A3[32][64]   = layer-3 "matrix": row 0 = W3 permuted to match the C2'
//                  fragment order, rows 1..31 = 0
__global__ void prep_kernel(const float* __restrict__ W1, const float* __restrict__ b1,
                            const float* __restrict__ W2, const float* __restrict__ b2,
                            const float* __restrict__ W3,
                            __hip_bfloat16* __restrict__ W1tb,
                            __hip_bfloat16* __restrict__ W2tb,
                            __hip_bfloat16* __restrict__ A3) {
    int i = blockIdx.x * 256 + threadIdx.x;
    if (i < H1 * 64) {
        int h = i >> 6, k = i & 63;
        float v = (k < 51) ? W1[k * H1 + h] : ((k == 51) ? b1[h] : 0.0f);
        W1tb[i] = __float2bfloat16(v);
    } else if (i < H1 * 64 + H2 * 144) {
        int j = i - H1 * 64;
        int h2 = j / 144, k = j - h2 * 144;
        float v;
        if (k < 128) {
            int kk = k >> 4, hb = (k >> 3) & 1, jj = k & 7;
            int hperm = (kk & 3) * 32 + 8 * (((kk >> 2) << 1) | (jj >> 2)) + (jj & 3) + 4 * hb;
            v = W2[hperm * H2 + h2];
        } else {
            v = (k == 128) ? b2[h2] : 0.0f;
        }
        W2tb[j] = __float2bfloat16(v);
    } else if (i < H1 * 64 + H2 * 144 + 32 * 64) {
        int j = i - (H1 * 64 + H2 * 144);
        int row = j >> 6, k = j & 63;
        float v = 0.0f;
        if (row == 0) {
            int kk = k >> 4, hb = (k >> 3) & 1, jj = k & 7;
            int f = kk & 1;
            int r = 8 * (kk >> 1) + jj;
            int h2 = 32 * f + (r & 3) + 8 * (r >> 2) + 4 * hb;
            v = W3[h2];
        }
        A3[j] = __float2bfloat16(v);
    }
}

// main: 1024 blocks x 4 waves; each wave computes 4 tiles of 32 output rows.
__global__ __launch_bounds__(256, 2)
void lpe_mfma_kernel(const float* __restrict__ pos,
                     const __hip_bfloat16* __restrict__ W1tb,
                     const __hip_bfloat16* __restrict__ W2tb,
                     const __hip_bfloat16* __restrict__ A3,
                     const float* __restrict__ b3,
                     float* __restrict__ out) {
    __shared__ float sp[16 * TILE_F];  // 4 waves x 4 tiles = 37.9 KB

    const int tid  = threadIdx.x;
    const int wid  = tid >> 6;
    const int lane = tid & 63;
    const int ml   = lane & 31;
    const int hi   = lane >> 5;

    const int batch = blockIdx.x >> 4;  // 64 batches x 16 blocks
    const int blk   = blockIdx.x & 15;
    const int wrow0 = blk * 512 + wid * 128;

    // ---- stage all 4 tiles (float4, 16B-aligned bases), wave-private LDS ----
    #pragma unroll
    for (int t = 0; t < 4; ++t) {
        float* dst = sp + (wid * 4 + t) * TILE_F;
        const int srow0 = wrow0 + t * 32;
        const float* src = pos + ((size_t)batch * SEQ + srow0) * NUM_POS;
        const int lim = (SEQ - srow0) * NUM_POS;  // >= 544; 544 only at global tail
        #pragma unroll
        for (int it = 0; it < 3; ++it) {
            int i = it * 64 + lane;
            if (i < 144) {
                f32x4 v;
                if (i * 4 + 4 <= lim) {
                    v = *reinterpret_cast<const f32x4*>(src + i * 4);
                } else {
                    v[0] = v[1] = v[2] = v[3] = 0.0f;
                }
                *reinterpret_cast<f32x4*>(dst + i * 4) = v;
            }
        }
        if (lane < 2) {
            int i = 576 + lane;
            dst[i] = (i < lim) ? src[i] : 0.0f;
        }
    }
    // same-wave ds_write -> ds_read: compiler-inserted lgkmcnt ordering suffices.

    const float b3v = b3[0];

    // constant bias B-fragment for GEMM2's k=128 step
    u32x4 b2cu; b2cu[0] = (hi == 0) ? 0x3f80u : 0u; b2cu[1] = 0u; b2cu[2] = 0u; b2cu[3] = 0u;
    const s16x8 B2C = __builtin_bit_cast(s16x8, b2cu);

    #pragma unroll 1
    for (int t = 0; t < 4; ++t) {
        const float* spw = sp + (wid * 4 + t) * TILE_F;
        const int srow0 = wrow0 + t * 32;

        // ---- B1 fragments: window(m) = contiguous 51 floats at m*17 ----
        const float* wbase = spw + ml * NUM_POS + 8 * hi;
        u32x4 B1u[4];
        #pragma unroll
        for (int kk = 0; kk < 4; ++kk) {
            float x[8];
            #pragma unroll
            for (int j = 0; j < 8; ++j) {
                if (kk < 3) {
                    x[j] = wbase[kk * 16 + j];
                } else {
                    if (j < 3) {
                        float v = wbase[48 + j];
                        x[j] = hi ? 0.0f : v;       // hi=1 slots are k=56..63 pad
                    } else if (j == 3) {
                        x[j] = hi ? 0.0f : 1.0f;    // k=51 bias column
                    } else {
                        x[j] = 0.0f;
                    }
                }
            }
            u32x4 u;
            u[0] = pkbf(x[0], x[1]); u[1] = pkbf(x[2], x[3]);
            u[2] = pkbf(x[4], x[5]); u[3] = pkbf(x[6], x[7]);
            B1u[kk] = u;
        }

        // ---- GEMM1': C1'[h][m], K=64 ----
        f32x16 acc1[4];
        #pragma unroll
        for (int hf = 0; hf < 4; ++hf) acc1[hf] = zero16();
        #pragma unroll
        for (int hf = 0; hf < 4; ++hf) {
            #pragma unroll
            for (int kk = 0; kk < 4; ++kk) {
                s16x8 a = *reinterpret_cast<const s16x8*>(
                    W1tb + ((hf * 32 + ml) * 64 + kk * 16 + hi * 8));
                acc1[hf] = __builtin_amdgcn_mfma_f32_32x32x16_bf16(
                    a, __builtin_bit_cast(s16x8, B1u[kk]), acc1[hf], 0, 0, 0);
            }
        }

        // ---- GEMM2': B-frag for step kk is relu(acc1[kk&3][8*(kk>>2)..+7]),
        //      contiguous thanks to the baked W2 k-permutation. No shuffles. ----
        f32x16 acc2[2];
        acc2[0] = zero16(); acc2[1] = zero16();
        #pragma unroll
        for (int kk = 0; kk < 8; ++kk) {
            const int hf = kk & 3;
            const int rb = (kk >> 2) * 8;
            u32x4 bu;
            bu[0] = pkbf(fmaxf(acc1[hf][rb + 0], 0.0f), fmaxf(acc1[hf][rb + 1], 0.0f));
            bu[1] = pkbf(fmaxf(acc1[hf][rb + 2], 0.0f), fmaxf(acc1[hf][rb + 3], 0.0f));
            bu[2] = pkbf(fmaxf(acc1[hf][rb + 4], 0.0f), fmaxf(acc1[hf][rb + 5], 0.0f));
            bu[3] = pkbf(fmaxf(acc1[hf][rb + 6], 0.0f), fmaxf(acc1[hf][rb + 7], 0.0f));
            const s16x8 bfrag = __builtin_bit_cast(s16x8, bu);
            #pragma unroll
            for (int f = 0; f < 2; ++f) {
                s16x8 a = *reinterpret_cast<const s16x8*>(
                    W2tb + ((f * 32 + ml) * 144 + kk * 16 + hi * 8));
                acc2[f] = __builtin_amdgcn_mfma_f32_32x32x16_bf16(a, bfrag, acc2[f], 0, 0, 0);
            }
        }
        #pragma unroll
        for (int f = 0; f < 2; ++f) {
            s16x8 a = *reinterpret_cast<const s16x8*>(
                W2tb + ((f * 32 + ml) * 144 + 128 + hi * 8));
            acc2[f] = __builtin_amdgcn_mfma_f32_32x32x16_bf16(a, B2C, acc2[f], 0, 0, 0);
        }

        // ---- GEMM3': layer-3 dot as 4 MFMAs. B-frag for step kk is
        //      relu(acc2[kk&1][8*(kk>>1)..+7]); A3 row 0 = permuted W3.
        //      Result: D[0][ml] lands in acc3[0] of hi=0 lanes. ----
        f32x16 acc3 = zero16();
        #pragma unroll
        for (int kk = 0; kk < 4; ++kk) {
            const int f  = kk & 1;
            const int rb = (kk >> 1) * 8;
            u32x4 bu;
            bu[0] = pkbf(fmaxf(acc2[f][rb + 0], 0.0f), fmaxf(acc2[f][rb + 1], 0.0f));
            bu[1] = pkbf(fmaxf(acc2[f][rb + 2], 0.0f), fmaxf(acc2[f][rb + 3], 0.0f));
            bu[2] = pkbf(fmaxf(acc2[f][rb + 4], 0.0f), fmaxf(acc2[f][rb + 5], 0.0f));
            bu[3] = pkbf(fmaxf(acc2[f][rb + 6], 0.0f), fmaxf(acc2[f][rb + 7], 0.0f));
            const s16x8 bfrag = __builtin_bit_cast(s16x8, bu);
            s16x8 a = *reinterpret_cast<const s16x8*>(
                A3 + (ml * 64 + kk * 16 + hi * 8));
            acc3 = __builtin_amdgcn_mfma_f32_32x32x16_bf16(a, bfrag, acc3, 0, 0, 0);
        }

        // ---- epilogue: sigmoid + store (hi=0 lanes hold D rows 0) ----
        if (hi == 0) {
            const int grow = srow0 + ml;
            if (grow < SEQ - 2) {
                float v = acc3[0] + b3v;
                out[(size_t)batch * (SEQ - 2) + grow] = 1.0f / (1.0f + __expf(-v));
            }
        }
    }
}

extern "C" void kernel_launch(void* const* d_in, const int* in_sizes, int n_in,
                              void* d_out, int out_size, void* d_ws, size_t ws_size,
                              hipStream_t stream) {
    const float* pos = (const float*)d_in[0];
    const float* W1  = (const float*)d_in[1];
    const float* b1  = (const float*)d_in[2];
    const float* W2  = (const float*)d_in[3];
    const float* b2  = (const float*)d_in[4];
    const float* W3  = (const float*)d_in[5];
    const float* b3  = (const float*)d_in[6];
    float* out = (float*)d_out;

    __hip_bfloat16* W1tb = (__hip_bfloat16*)d_ws;                   // 8192  bf16 = 16 KB
    __hip_bfloat16* W2tb = (__hip_bfloat16*)((char*)d_ws + 16384);  // 9216  bf16 = 18 KB
    __hip_bfloat16* A3   = (__hip_bfloat16*)((char*)d_ws + 34816);  // 2048  bf16 =  4 KB

    const int prep_elems = H1 * 64 + H2 * 144 + 32 * 64;  // 19456
    prep_kernel<<<(prep_elems + 255) / 256, 256, 0, stream>>>(W1, b1, W2, b2, W3,
                                                              W1tb, W2tb, A3);

    // 64 batches x 16 blocks; each block = 4 waves x 4 tiles x 32 rows = 512 rows
    lpe_mfma_kernel<<<BATCH * 16, 256, 0, stream>>>(pos, W1tb, W2tb, A3, b3, out);
}

// Round 5
// 46.842 us; speedup vs baseline: 4.1467x; 1.0097x over previous
//
#include <hip/hip_runtime.h>
#include <hip/hip_bf16.h>
#include <math.h>

#define NUM_POS 17
#define SEQ 8192
#define BATCH 64
#define H1 128
#define H2 64
#define TILE_F 592  // floats per 32-row tile region (578 used + pad)

typedef __attribute__((ext_vector_type(8)))  short        s16x8;
typedef __attribute__((ext_vector_type(16))) float        f32x16;
typedef __attribute__((ext_vector_type(4)))  unsigned int u32x4;
typedef __attribute__((ext_vector_type(4)))  float        f32x4;

static __device__ __forceinline__ unsigned pkbf(float a, float b) {
    unsigned short ua = __builtin_bit_cast(unsigned short, __float2bfloat16(a));
    unsigned short ub = __builtin_bit_cast(unsigned short, __float2bfloat16(b));
    return (unsigned)ua | ((unsigned)ub << 16);
}

// relu + pack two accumulator elements
static __device__ __forceinline__ unsigned pkrelu(float a, float b) {
    return pkbf(fmaxf(a, 0.0f), fmaxf(b, 0.0f));
}

static __device__ __forceinline__ f32x16 zero16() {
    f32x16 z;
    #pragma unroll
    for (int i = 0; i < 16; ++i) z[i] = 0.0f;
    return z;
}

// prep:
//  W1tb[h][64]  = W1^T padded (col 51 = b1, cols 52..63 = 0)
//  W2tb[h2][144] = W2^T with k-dim permuted to match the C1' fragment order
//                  (col 128 = b2, cols 129..143 = 0)
//  A3[32][64]   = layer-3 "matrix": row 0 = W3 permuted to match the C2'
//                  fragment order, rows 1..31 = 0
__global__ void prep_kernel(const float* __restrict__ W1, const float* __restrict__ b1,
                            const float* __restrict__ W2, const float* __restrict__ b2,
                            const float* __restrict__ W3,
                            __hip_bfloat16* __restrict__ W1tb,
                            __hip_bfloat16* __restrict__ W2tb,
                            __hip_bfloat16* __restrict__ A3) {
    int i = blockIdx.x * 256 + threadIdx.x;
    if (i < H1 * 64) {
        int h = i >> 6, k = i & 63;
        float v = (k < 51) ? W1[k * H1 + h] : ((k == 51) ? b1[h] : 0.0f);
        W1tb[i] = __float2bfloat16(v);
    } else if (i < H1 * 64 + H2 * 144) {
        int j = i - H1 * 64;
        int h2 = j / 144, k = j - h2 * 144;
        float v;
        if (k < 128) {
            int kk = k >> 4, hb = (k >> 3) & 1, jj = k & 7;
            int hperm = (kk & 3) * 32 + 8 * (((kk >> 2) << 1) | (jj >> 2)) + (jj & 3) + 4 * hb;
            v = W2[hperm * H2 + h2];
        } else {
            v = (k == 128) ? b2[h2] : 0.0f;
        }
        W2tb[j] = __float2bfloat16(v);
    } else if (i < H1 * 64 + H2 * 144 + 32 * 64) {
        int j = i - (H1 * 64 + H2 * 144);
        int row = j >> 6, k = j & 63;
        float v = 0.0f;
        if (row == 0) {
            int kk = k >> 4, hb = (k >> 3) & 1, jj = k & 7;
            int f = kk & 1;
            int r = 8 * (kk >> 1) + jj;
            int h2 = 32 * f + (r & 3) + 8 * (r >> 2) + 4 * hb;
            v = W3[h2];
        }
        A3[j] = __float2bfloat16(v);
    }
}

// main: 1024 blocks x 4 waves; each wave computes 4 tiles of 32 output rows.
__global__ __launch_bounds__(256, 2)
void lpe_mfma_kernel(const float* __restrict__ pos,
                     const __hip_bfloat16* __restrict__ W1tb,
                     const __hip_bfloat16* __restrict__ W2tb,
                     const __hip_bfloat16* __restrict__ A3,
                     const float* __restrict__ b3,
                     float* __restrict__ out) {
    __shared__ float sp[16 * TILE_F];  // 4 waves x 4 tiles = 37.9 KB

    const int tid  = threadIdx.x;
    const int wid  = tid >> 6;
    const int lane = tid & 63;
    const int ml   = lane & 31;
    const int hi   = lane >> 5;

    const int batch = blockIdx.x >> 4;  // 64 batches x 16 blocks
    const int blk   = blockIdx.x & 15;
    const int wrow0 = blk * 512 + wid * 128;

    // ---- stage all 4 tiles (float4, 16B-aligned bases), wave-private LDS ----
    #pragma unroll
    for (int t = 0; t < 4; ++t) {
        float* dst = sp + (wid * 4 + t) * TILE_F;
        const int srow0 = wrow0 + t * 32;
        const float* src = pos + ((size_t)batch * SEQ + srow0) * NUM_POS;
        const int lim = (SEQ - srow0) * NUM_POS;  // >= 544; 544 only at global tail
        #pragma unroll
        for (int it = 0; it < 3; ++it) {
            int i = it * 64 + lane;
            if (i < 144) {
                f32x4 v;
                if (i * 4 + 4 <= lim) {
                    v = *reinterpret_cast<const f32x4*>(src + i * 4);
                } else {
                    v[0] = v[1] = v[2] = v[3] = 0.0f;
                }
                *reinterpret_cast<f32x4*>(dst + i * 4) = v;
            }
        }
        if (lane < 2) {
            int i = 576 + lane;
            dst[i] = (i < lim) ? src[i] : 0.0f;
        }
    }
    // same-wave ds_write -> ds_read: compiler-inserted lgkmcnt ordering suffices.

    const float b3v = b3[0];

    // constant bias B-fragment for GEMM2's k=128 step
    u32x4 b2cu; b2cu[0] = (hi == 0) ? 0x3f80u : 0u; b2cu[1] = 0u; b2cu[2] = 0u; b2cu[3] = 0u;
    const s16x8 B2C = __builtin_bit_cast(s16x8, b2cu);

    #pragma unroll 1
    for (int t = 0; t < 4; ++t) {
        const float* spw = sp + (wid * 4 + t) * TILE_F;
        const int srow0 = wrow0 + t * 32;

        // ---- B1 fragments: window(m) = contiguous 51 floats at m*17 ----
        const float* wbase = spw + ml * NUM_POS + 8 * hi;
        u32x4 B1u[4];
        #pragma unroll
        for (int kk = 0; kk < 4; ++kk) {
            float x[8];
            #pragma unroll
            for (int j = 0; j < 8; ++j) {
                if (kk < 3) {
                    x[j] = wbase[kk * 16 + j];
                } else {
                    if (j < 3) {
                        float v = wbase[48 + j];
                        x[j] = hi ? 0.0f : v;       // hi=1 slots are k=56..63 pad
                    } else if (j == 3) {
                        x[j] = hi ? 0.0f : 1.0f;    // k=51 bias column
                    } else {
                        x[j] = 0.0f;
                    }
                }
            }
            u32x4 u;
            u[0] = pkbf(x[0], x[1]); u[1] = pkbf(x[2], x[3]);
            u[2] = pkbf(x[4], x[5]); u[3] = pkbf(x[6], x[7]);
            B1u[kk] = u;
        }

        // ---- GEMM1': C1'[h][m], K=64 ----
        f32x16 acc1[4];
        #pragma unroll
        for (int hf = 0; hf < 4; ++hf) acc1[hf] = zero16();
        #pragma unroll
        for (int hf = 0; hf < 4; ++hf) {
            #pragma unroll
            for (int kk = 0; kk < 4; ++kk) {
                s16x8 a = *reinterpret_cast<const s16x8*>(
                    W1tb + ((hf * 32 + ml) * 64 + kk * 16 + hi * 8));
                acc1[hf] = __builtin_amdgcn_mfma_f32_32x32x16_bf16(
                    a, __builtin_bit_cast(s16x8, B1u[kk]), acc1[hf], 0, 0, 0);
            }
        }

        // ---- eager relu+pack: acc1 (64 f32 regs) -> pk1 (32 u32 regs), acc1 dies ----
        unsigned pk1[4][8];
        #pragma unroll
        for (int hf = 0; hf < 4; ++hf)
            #pragma unroll
            for (int j = 0; j < 8; ++j)
                pk1[hf][j] = pkrelu(acc1[hf][2 * j], acc1[hf][2 * j + 1]);

        // ---- GEMM2': B-frag for step kk = pk1[kk&3][4*(kk>>2) .. +3] ----
        f32x16 acc2[2];
        acc2[0] = zero16(); acc2[1] = zero16();
        #pragma unroll
        for (int kk = 0; kk < 8; ++kk) {
            const int hf = kk & 3;
            const int jb = (kk >> 2) * 4;
            u32x4 bu;
            bu[0] = pk1[hf][jb + 0];
            bu[1] = pk1[hf][jb + 1];
            bu[2] = pk1[hf][jb + 2];
            bu[3] = pk1[hf][jb + 3];
            const s16x8 bfrag = __builtin_bit_cast(s16x8, bu);
            #pragma unroll
            for (int f = 0; f < 2; ++f) {
                s16x8 a = *reinterpret_cast<const s16x8*>(
                    W2tb + ((f * 32 + ml) * 144 + kk * 16 + hi * 8));
                acc2[f] = __builtin_amdgcn_mfma_f32_32x32x16_bf16(a, bfrag, acc2[f], 0, 0, 0);
            }
        }
        #pragma unroll
        for (int f = 0; f < 2; ++f) {
            s16x8 a = *reinterpret_cast<const s16x8*>(
                W2tb + ((f * 32 + ml) * 144 + 128 + hi * 8));
            acc2[f] = __builtin_amdgcn_mfma_f32_32x32x16_bf16(a, B2C, acc2[f], 0, 0, 0);
        }

        // ---- eager relu+pack: acc2 -> pk2 (16 u32), acc2 dies ----
        unsigned pk2[2][8];
        #pragma unroll
        for (int f = 0; f < 2; ++f)
            #pragma unroll
            for (int j = 0; j < 8; ++j)
                pk2[f][j] = pkrelu(acc2[f][2 * j], acc2[f][2 * j + 1]);

        // ---- GEMM3': B-frag for step kk = pk2[kk&1][4*(kk>>1) .. +3] ----
        f32x16 acc3 = zero16();
        #pragma unroll
        for (int kk = 0; kk < 4; ++kk) {
            const int f  = kk & 1;
            const int jb = (kk >> 1) * 4;
            u32x4 bu;
            bu[0] = pk2[f][jb + 0];
            bu[1] = pk2[f][jb + 1];
            bu[2] = pk2[f][jb + 2];
            bu[3] = pk2[f][jb + 3];
            const s16x8 bfrag = __builtin_bit_cast(s16x8, bu);
            s16x8 a = *reinterpret_cast<const s16x8*>(
                A3 + (ml * 64 + kk * 16 + hi * 8));
            acc3 = __builtin_amdgcn_mfma_f32_32x32x16_bf16(a, bfrag, acc3, 0, 0, 0);
        }

        // ---- epilogue: sigmoid + store (hi=0 lanes hold D row 0) ----
        if (hi == 0) {
            const int grow = srow0 + ml;
            if (grow < SEQ - 2) {
                float v = acc3[0] + b3v;
                out[(size_t)batch * (SEQ - 2) + grow] = 1.0f / (1.0f + __expf(-v));
            }
        }
    }
}

extern "C" void kernel_launch(void* const* d_in, const int* in_sizes, int n_in,
                              void* d_out, int out_size, void* d_ws, size_t ws_size,
                              hipStream_t stream) {
    const float* pos = (const float*)d_in[0];
    const float* W1  = (const float*)d_in[1];
    const float* b1  = (const float*)d_in[2];
    const float* W2  = (const float*)d_in[3];
    const float* b2  = (const float*)d_in[4];
    const float* W3  = (const float*)d_in[5];
    const float* b3  = (const float*)d_in[6];
    float* out = (float*)d_out;

    __hip_bfloat16* W1tb = (__hip_bfloat16*)d_ws;                   // 8192  bf16 = 16 KB
    __hip_bfloat16* W2tb = (__hip_bfloat16*)((char*)d_ws + 16384);  // 9216  bf16 = 18 KB
    __hip_bfloat16* A3   = (__hip_bfloat16*)((char*)d_ws + 34816);  // 2048  bf16 =  4 KB

    const int prep_elems = H1 * 64 + H2 * 144 + 32 * 64;  // 19456
    prep_kernel<<<(prep_elems + 255) / 256, 256, 0, stream>>>(W1, b1, W2, b2, W3,
                                                              W1tb, W2tb, A3);

    // 64 batches x 16 blocks; each block = 4 waves x 4 tiles x 32 rows = 512 rows
    lpe_mfma_kernel<<<BATCH * 16, 256, 0, stream>>>(pos, W1tb, W2tb, A3, b3, out);
}